// Round 11
// baseline (444.449 us; speedup 1.0000x reference)
//
#include <hip/hip_runtime.h>

// 2-layer LSTM (H=50) + linear head — MFMA v6: 12-wave async gang pipeline.
//
// Round-9/10: async counters alone were neutral (399 us, VALUBusy 57%,
// 2 waves/SIMD, ~870 cyc/step bubbles). Binder = latency w/ too few waves.
// Fix: 3 waves/SIMD. waves/SIMD = floor(512/VGPR); L1 needs ~140 regs, so
// cap 170 (launch_bounds(768,3)) admits 3. Block = 12 waves:
//   waves 0-3:  L0 gang (ub = wid), 4 EW rows each  (8 MFMA + 4 bodies)
//   waves 4-11: L1 gang (ub = (wid-4)&3, sub = (wid-4)>>2): sub pairs
//     duplicate the MFMA (MfmaUtil has headroom) and split EW rows
//     {0,1}/{2,3} statically                        (16 MFMA + 2 bodies)
// Per SIMD: 1 L0 + 2 L1 waves at different pipeline phases.
//
// Async protocol (identical to round 9, gang sizes 4 and 8):
//   L0 @s: ctr0 >= 4s; before storing (s>=4): ctr1 >= 8(s-3) (ring slot free)
//   L1 @t: ctr0 >= 4(t+1) (h0(t) ready); ctr1 >= 8t (own gang done t-1)
//   head:  ctr1 >= 8*TT
// Gang-complete counters serialize ring/h1b reuse (no races, no deadlock:
// L0 can run up to 4 steps ahead, then throttles on L1).
//
// K layout per batch (f16): ring row = [h0 0..49 | x 50,51 | 1.0 @52 | pad];
// h1 row = [h1 0..49 | pad]. Weights pre-scaled (i,f,o: -log2e; g: +2log2e;
// c kept in 2log2e domain) -> fused-rcp elementwise, 8 trans/body.

typedef _Float16 f16;
typedef f16  f16x8 __attribute__((ext_vector_type(8)));
typedef float f32x4 __attribute__((ext_vector_type(4)));
typedef unsigned short u16;
typedef unsigned int   u32;

#define TT   512
#define MB   16     // batches per block (= MFMA M)
#define RK   72     // ring/h1 row length in f16 (144 B)
#define XTP  513    // xpack row pad (column reads conflict-free)
#define BLK  768    // 12 waves

#define EXP2(v) __builtin_amdgcn_exp2f(v)
__device__ __forceinline__ float rcp_(float v) { return __builtin_amdgcn_rcpf(v); }

#define L2E  1.4426950408889634f
#define L2E2 2.8853900817779268f

// Weight element for B-fragment position (layer, gate g, out-unit u, k),
// pre-scaled: gates i,f,o (g=0,1,3) by -log2e; gate g (g=2) by +2*log2e.
__device__ __forceinline__ float welem(int layer, int g, int u, int k,
        const float* __restrict__ Wih0, const float* __restrict__ Whh0,
        const float* __restrict__ b0,
        const float* __restrict__ Wih1, const float* __restrict__ Whh1,
        const float* __restrict__ b1) {
    if (u >= 50) return 0.0f;
    const float s = (g == 2) ? L2E2 : -L2E;
    const int row = g * 50 + u;           // PyTorch gate order i,f,g,o
    if (layer == 0) {
        if (k < 50)  return s * Whh0[row * 50 + k];
        if (k < 52)  return s * Wih0[row * 2 + (k - 50)];
        if (k == 52) return s * b0[row];
        return 0.0f;
    } else {
        if (k < 50)             return s * Wih1[row * 50 + k];
        if (k == 52)            return s * b1[row];
        if (k >= 64 && k < 114) return s * Whh1[row * 50 + (k - 64)];
        return 0.0f;
    }
}

// Fused elementwise: pre-scaled gate sums, cell state in L2E2 domain.
// i*g' = L2E2*(eG-1)*rcp((1+eI)(1+eG)); h = (eC-1)*rcp((1+eO)(eC+1)).
#define EWFUSED(YI, YF, YG, YO, CS, HOUT)                                     \
    {                                                                         \
        const float eI = EXP2(YI);                                            \
        const float eF = EXP2(YF);                                            \
        const float eG = EXP2(YG);                                            \
        const float eO = EXP2(YO);                                            \
        const float fg  = rcp_(1.0f + eF);                                    \
        const float num = fmaf(L2E2, eG, -L2E2);                              \
        const float igg = num * rcp_((1.0f + eI) * (1.0f + eG));              \
        CS = fmaf(fg, CS, igg);                                               \
        const float cc = fminf(fmaxf(CS, -80.0f), 80.0f);                     \
        const float eC = EXP2(cc);                                            \
        HOUT = (eC - 1.0f) * rcp_((1.0f + eO) * (eC + 1.0f));                 \
    }

extern "C" __global__ void __launch_bounds__(BLK, 3)
lstm2_async12(const float* __restrict__ x,
              const float* __restrict__ W_ih0, const float* __restrict__ W_hh0,
              const float* __restrict__ b0,
              const float* __restrict__ W_ih1, const float* __restrict__ W_hh1,
              const float* __restrict__ b1,
              const float* __restrict__ W_fc,  const float* __restrict__ b_fc,
              float* __restrict__ out)
{
    __shared__ __align__(16) u16 ring[4][MB][RK];   // 9.2 KB h0 ring (+x,+bias)
    __shared__ __align__(16) u16 h1b[2][MB][RK];    // 4.6 KB h1 double buffer
    __shared__ u32   xpack[MB][XTP];                // 32.8 KB packed f16 x
    __shared__ float hfin[MB][52];                  // final h1 fp32 for head
    __shared__ u32   ctr0, ctr1;                    // gang progress counters

    const int tid   = threadIdx.x;
    const int lane  = tid & 63;
    const int wid   = tid >> 6;        // 0..11
    const int layer = (wid >= 4);      // 0: waves 0-3, 1: waves 4-11
    const int lidx  = layer ? (wid - 4) : wid;
    const int ub    = lidx & 3;        // unit-block (16 units)
    const int sub   = lidx >> 2;       // L1 EW row-half (0 or 1); L0: always 0
    const int col   = lane & 15;       // A-row (batch) / B-col (unit) / D-col
    const int kg    = lane >> 4;       // k-octet / D-row group
    const int bbase = blockIdx.x * MB;

    // ---- stage x -> packed f16 pairs (coalesced float2 loads) ----
    for (int idx = tid; idx < MB * TT; idx += BLK) {
        const int b = idx >> 9, t = idx & (TT - 1);
        const float2 v = *reinterpret_cast<const float2*>(
            x + ((size_t)(bbase + b) * TT + t) * 2);
        xpack[b][t] = (u32)__builtin_bit_cast(u16, (f16)v.x)
                    | ((u32)__builtin_bit_cast(u16, (f16)v.y) << 16);
    }
    // ---- zero ring + h1b (pads stay 0 forever) ----
    {
        u32* p = reinterpret_cast<u32*>(&ring[0][0][0]);
        for (int i = tid; i < (int)(sizeof(ring) / 4); i += BLK) p[i] = 0;
        u32* q = reinterpret_cast<u32*>(&h1b[0][0][0]);
        for (int i = tid; i < (int)(sizeof(h1b) / 4); i += BLK) q[i] = 0;
    }
    if (tid == 0) { ctr0 = 0; ctr1 = 0; }
    __syncthreads();
    // bias slot k=52 (f16 1.0) in all 4 ring slots; x(0) into slot 3
    if (tid < 64) ring[tid >> 4][tid & 15][52] = (u16)0x3C00;
    else if (tid < 80)
        *reinterpret_cast<u32*>(&ring[3][tid - 64][50]) = xpack[tid - 64][0];

    // ---- static weight B-fragments (constant-bound loops -> registers) ----
    // B map: lane l, elem e <-> B[k = kf*32 + 8*kg + e][n = col]; identical
    // (lane,e)->k map as the A reads -> in-octet permutations cancel.
    const int u = 16 * ub + col;
    f16x8 bf[4][4];    // [gate][kf]; L0 kf=2,3 all-zero (only read on L1 path)
#pragma unroll
    for (int g = 0; g < 4; ++g) {
#pragma unroll
        for (int kf = 0; kf < 4; ++kf) {
            f16x8 v;
#pragma unroll
            for (int e = 0; e < 8; ++e)
                v[e] = (f16)welem(layer, g, u, kf * 32 + 8 * kg + e,
                                  W_ih0, W_hh0, b0, W_ih1, W_hh1, b1);
            bf[g][kf] = v;
        }
    }

    __syncthreads();   // LAST barrier in the kernel

    volatile u32* vc0 = &ctr0;
    volatile u32* vc1 = &ctr1;
    float cst[4] = {0.f, 0.f, 0.f, 0.f};   // cell state (L2E2 domain)
    const f32x4 z = {0.f, 0.f, 0.f, 0.f};

    if (layer == 0) {
        // =================== L0 gang (4 waves): producer ===================
        for (int s = 0; s < TT; ++s) {
            while (*vc0 < (u32)(4 * s)) __builtin_amdgcn_s_sleep(1);
            const int rs = (s + 3) & 3, ws = s & 3;
            const f16x8 a0 = *reinterpret_cast<const f16x8*>(&ring[rs][col][8 * kg]);
            const f16x8 a1 = *reinterpret_cast<const f16x8*>(&ring[rs][col][32 + 8 * kg]);
            f32x4 acc[4];
            __builtin_amdgcn_s_setprio(1);
#pragma unroll
            for (int g = 0; g < 4; ++g) {
                f32x4 c = __builtin_amdgcn_mfma_f32_16x16x32_f16(a0, bf[g][0], z, 0, 0, 0);
                acc[g]  = __builtin_amdgcn_mfma_f32_16x16x32_f16(a1, bf[g][1], c, 0, 0, 0);
            }
            __builtin_amdgcn_s_setprio(0);
            u16 hw[4];
#pragma unroll
            for (int r = 0; r < 4; ++r) {
                float hv;
                EWFUSED(acc[0][r], acc[1][r], acc[2][r], acc[3][r], cst[r], hv);
                hw[r] = __builtin_bit_cast(u16, (f16)hv);
            }
            // ring slot s%4 must be free of L1's step s-4 reads (gang of 8)
            if (s >= 4)
                while (*vc1 < (u32)(8 * (s - 3))) __builtin_amdgcn_s_sleep(1);
            if (u < 50) {
#pragma unroll
                for (int r = 0; r < 4; ++r) ring[ws][4 * kg + r][u] = hw[r];
            }
            if (wid == 0 && lane < MB && (s + 1) < TT)
                *reinterpret_cast<u32*>(&ring[ws][lane][50]) = xpack[lane][s + 1];
            __threadfence_block();
            if (lane == 0) atomicAdd(&ctr0, 1u);
        }
    } else {
        // ============ L1 gang (8 waves): consumer, EW row-split ============
        for (int t = 0; t < TT; ++t) {
            while (*vc0 < (u32)(4 * (t + 1))) __builtin_amdgcn_s_sleep(1);
            while (*vc1 < (u32)(8 * t))       __builtin_amdgcn_s_sleep(1);
            const int rs = t & 3, wb = t & 1, rb = wb ^ 1;
            const f16x8 a0 = *reinterpret_cast<const f16x8*>(&ring[rs][col][8 * kg]);
            const f16x8 a1 = *reinterpret_cast<const f16x8*>(&ring[rs][col][32 + 8 * kg]);
            const f16x8 a2 = *reinterpret_cast<const f16x8*>(&h1b[rb][col][8 * kg]);
            const f16x8 a3 = *reinterpret_cast<const f16x8*>(&h1b[rb][col][32 + 8 * kg]);
            f32x4 acc[4];
            __builtin_amdgcn_s_setprio(1);
#pragma unroll
            for (int g = 0; g < 4; ++g) {
                f32x4 c = __builtin_amdgcn_mfma_f32_16x16x32_f16(a0, bf[g][0], z, 0, 0, 0);
                c       = __builtin_amdgcn_mfma_f32_16x16x32_f16(a1, bf[g][1], c, 0, 0, 0);
                c       = __builtin_amdgcn_mfma_f32_16x16x32_f16(a2, bf[g][2], c, 0, 0, 0);
                acc[g]  = __builtin_amdgcn_mfma_f32_16x16x32_f16(a3, bf[g][3], c, 0, 0, 0);
            }
            __builtin_amdgcn_s_setprio(0);
            // EW: this wave's 2 rows only (static under wave-uniform sub)
#define L1EW(R, CS)                                                           \
            {                                                                 \
                const int bat = 4 * kg + (R);                                 \
                float hv;                                                     \
                EWFUSED(acc[0][R], acc[1][R], acc[2][R], acc[3][R], CS, hv);  \
                if (u < 50) {                                                 \
                    h1b[wb][bat][u] = __builtin_bit_cast(u16, (f16)hv);       \
                    if (t == TT - 1) hfin[bat][u] = hv;                       \
                }                                                             \
            }
            if (sub == 0) { L1EW(0, cst[0]) L1EW(1, cst[1]) }
            else          { L1EW(2, cst[0]) L1EW(3, cst[1]) }
#undef L1EW
            __threadfence_block();
            if (lane == 0) atomicAdd(&ctr1, 1u);
        }
        // ---- final linear head on fp32 h1[T-1] (after whole L1 gang done) ----
        if (wid == 4) {
            while (*vc1 < (u32)(8 * TT)) __builtin_amdgcn_s_sleep(1);
            if (lane < MB) {
                float d = b_fc[0];
#pragma unroll
                for (int uu = 0; uu < 50; ++uu)
                    d = fmaf(W_fc[uu], hfin[lane][uu], d);
                out[bbase + lane] = d;
            }
        }
    }
}

extern "C" void kernel_launch(void* const* d_in, const int* in_sizes, int n_in,
                              void* d_out, int out_size, void* d_ws, size_t ws_size,
                              hipStream_t stream) {
    const float* x     = (const float*)d_in[0];
    const float* W_ih0 = (const float*)d_in[1];
    const float* W_hh0 = (const float*)d_in[2];
    const float* b0    = (const float*)d_in[3];
    const float* W_ih1 = (const float*)d_in[4];
    const float* W_hh1 = (const float*)d_in[5];
    const float* b1    = (const float*)d_in[6];
    const float* W_fc  = (const float*)d_in[7];
    const float* b_fc  = (const float*)d_in[8];
    float* out = (float*)d_out;

    const int B = in_sizes[0] / (TT * 2);    // 4096
    dim3 grid(B / MB), block(BLK);           // 256 blocks = 1 per CU
    hipLaunchKernelGGL(lstm2_async12, grid, block, 0, stream,
                       x, W_ih0, W_hh0, b0, W_ih1, W_hh1, b1, W_fc, b_fc, out);
}

// Round 12
// 436.638 us; speedup vs baseline: 1.0179x; 1.0179x over previous
//
#include <hip/hip_runtime.h>

// 2-layer LSTM (H=50) + linear head — MFMA v7: async pipeline, atomic-free sync.
//
// Round-10/11 lesson: period is sync-LATENCY-bound, not issue-bound.
//   - s_sleep(1) = 64-cyc quantum -> 200-400 cyc/step wake latency
//   - LDS atomicAdd on ONE address serializes: 8-12/step = 400-600 cyc
// Fix (work content identical to round 10):
//   - per-wave flag words f0[4]/f1[4] at 64B stride (no shared-address traffic)
//     writer: threadfence_block + plain volatile ds_write by lane 0
//     waiter: busy-spin on 4 volatile reads, NO s_sleep (wake <= ~130 cyc)
//   - L1 MFMA: two independent 2-chains + f32x4 add (halves serial latency)
//
// Structure (unchanged): 8 waves. Waves 0-3 = L0 gang (producer), waves 4-7 =
// L1 gang (consumer, lags 1 step). h0 flows through a 4-deep LDS ring
// (row = [h0 0..49 | x 50,51 | 1.0 @52 | pad]); h1 double-buffered.
// Protocol: L0 @s: all f0 >= s; before store (s>=4): all f1 >= s-3.
//           L1 @t: all f0 >= t+1 and all f1 >= t.   head: all f1 >= TT.
// Weights pre-scaled (i,f,o: -log2e; g: +2log2e; c in 2log2e domain) ->
// fused-rcp elementwise (5 exp2 + 3 rcp per body). Weights = static
// B-fragments in registers; MB=16 batches/block; grid 256 = 1 block/CU.

typedef _Float16 f16;
typedef f16  f16x8 __attribute__((ext_vector_type(8)));
typedef float f32x4 __attribute__((ext_vector_type(4)));
typedef unsigned short u16;
typedef unsigned int   u32;

#define TT   512
#define MB   16     // batches per block (= MFMA M)
#define RK   72     // ring/h1 row length in f16 (144 B)
#define XTP  513    // xpack row pad (column reads conflict-free)
#define BLK  512    // 8 waves

#define EXP2(v) __builtin_amdgcn_exp2f(v)
__device__ __forceinline__ float rcp_(float v) { return __builtin_amdgcn_rcpf(v); }

#define L2E  1.4426950408889634f
#define L2E2 2.8853900817779268f

// Weight element for B-fragment position (layer, gate g, out-unit u, k),
// pre-scaled: gates i,f,o (g=0,1,3) by -log2e; gate g (g=2) by +2*log2e.
__device__ __forceinline__ float welem(int layer, int g, int u, int k,
        const float* __restrict__ Wih0, const float* __restrict__ Whh0,
        const float* __restrict__ b0,
        const float* __restrict__ Wih1, const float* __restrict__ Whh1,
        const float* __restrict__ b1) {
    if (u >= 50) return 0.0f;
    const float s = (g == 2) ? L2E2 : -L2E;
    const int row = g * 50 + u;           // PyTorch gate order i,f,g,o
    if (layer == 0) {
        if (k < 50)  return s * Whh0[row * 50 + k];
        if (k < 52)  return s * Wih0[row * 2 + (k - 50)];
        if (k == 52) return s * b0[row];
        return 0.0f;
    } else {
        if (k < 50)             return s * Wih1[row * 50 + k];
        if (k == 52)            return s * b1[row];
        if (k >= 64 && k < 114) return s * Whh1[row * 50 + (k - 64)];
        return 0.0f;
    }
}

// Fused elementwise: pre-scaled gate sums, cell state in L2E2 domain.
// i*g' = L2E2*(eG-1)*rcp((1+eI)(1+eG)); h = (eC-1)*rcp((1+eO)(eC+1)).
#define EWFUSED(YI, YF, YG, YO, CS, HOUT)                                     \
    {                                                                         \
        const float eI = EXP2(YI);                                            \
        const float eF = EXP2(YF);                                            \
        const float eG = EXP2(YG);                                            \
        const float eO = EXP2(YO);                                            \
        const float fg  = rcp_(1.0f + eF);                                    \
        const float num = fmaf(L2E2, eG, -L2E2);                              \
        const float igg = num * rcp_((1.0f + eI) * (1.0f + eG));              \
        CS = fmaf(fg, CS, igg);                                               \
        const float cc = fminf(fmaxf(CS, -80.0f), 80.0f);                     \
        const float eC = EXP2(cc);                                            \
        HOUT = (eC - 1.0f) * rcp_((1.0f + eO) * (eC + 1.0f));                 \
    }

// Busy-spin until all 4 gang flags (stride 16 u32 = 64 B) reach tgt.
__device__ __forceinline__ void wait_gang(volatile const u32* f, u32 tgt) {
    for (;;) {
        const u32 a = f[0], b = f[16], c = f[32], d = f[48];
        if (a >= tgt && b >= tgt && c >= tgt && d >= tgt) break;
    }
    asm volatile("" ::: "memory");   // no data-read hoisting above the wait
}
__device__ __forceinline__ void wait_gang2(volatile const u32* fa, u32 ta,
                                           volatile const u32* fb, u32 tb) {
    for (;;) {
        const u32 a0 = fa[0], a1 = fa[16], a2 = fa[32], a3 = fa[48];
        const u32 b0 = fb[0], b1 = fb[16], b2 = fb[32], b3 = fb[48];
        if (a0 >= ta && a1 >= ta && a2 >= ta && a3 >= ta &&
            b0 >= tb && b1 >= tb && b2 >= tb && b3 >= tb) break;
    }
    asm volatile("" ::: "memory");
}

extern "C" __global__ void __launch_bounds__(BLK, 2)
lstm2_flags(const float* __restrict__ x,
            const float* __restrict__ W_ih0, const float* __restrict__ W_hh0,
            const float* __restrict__ b0,
            const float* __restrict__ W_ih1, const float* __restrict__ W_hh1,
            const float* __restrict__ b1,
            const float* __restrict__ W_fc,  const float* __restrict__ b_fc,
            float* __restrict__ out)
{
    __shared__ __align__(16) u16 ring[4][MB][RK];   // 9.2 KB h0 ring (+x,+bias)
    __shared__ __align__(16) u16 h1b[2][MB][RK];    // 4.6 KB h1 double buffer
    __shared__ u32   xpack[MB][XTP];                // 32.8 KB packed f16 x
    __shared__ float hfin[MB][52];                  // final h1 fp32 for head
    __shared__ u32   f0[4][16], f1[4][16];          // per-wave flags, 64B stride

    const int tid   = threadIdx.x;
    const int lane  = tid & 63;
    const int wid   = tid >> 6;        // 0..7
    const int layer = wid >> 2;        // waves 0-3: L0 gang, 4-7: L1 gang
    const int gw    = wid & 3;         // wave index within gang
    const int ub    = gw;              // unit-block (16 units)
    const int col   = lane & 15;       // A-row (batch) / B-col (unit) / D-col
    const int kg    = lane >> 4;       // k-octet / D-row group
    const int bbase = blockIdx.x * MB;

    // ---- stage x -> packed f16 pairs (coalesced float2 loads) ----
    for (int idx = tid; idx < MB * TT; idx += BLK) {
        const int b = idx >> 9, t = idx & (TT - 1);
        const float2 v = *reinterpret_cast<const float2*>(
            x + ((size_t)(bbase + b) * TT + t) * 2);
        xpack[b][t] = (u32)__builtin_bit_cast(u16, (f16)v.x)
                    | ((u32)__builtin_bit_cast(u16, (f16)v.y) << 16);
    }
    // ---- zero ring + h1b (pads stay 0 forever) + flags ----
    {
        u32* p = reinterpret_cast<u32*>(&ring[0][0][0]);
        for (int i = tid; i < (int)(sizeof(ring) / 4); i += BLK) p[i] = 0;
        u32* q = reinterpret_cast<u32*>(&h1b[0][0][0]);
        for (int i = tid; i < (int)(sizeof(h1b) / 4); i += BLK) q[i] = 0;
    }
    if (tid < 64) f0[tid >> 4][tid & 15] = 0;
    else if (tid < 128) f1[(tid - 64) >> 4][tid & 15] = 0;
    __syncthreads();
    // bias slot k=52 (f16 1.0) in all 4 ring slots; x(0) into slot 3
    if (tid < 64) ring[tid >> 4][tid & 15][52] = (u16)0x3C00;
    else if (tid < 80)
        *reinterpret_cast<u32*>(&ring[3][tid - 64][50]) = xpack[tid - 64][0];

    // ---- static weight B-fragments (constant-bound loops -> registers) ----
    // B map: lane l, elem e <-> B[k = kf*32 + 8*kg + e][n = col]; identical
    // (lane,e)->k map as the A reads -> in-octet permutations cancel.
    const int u = 16 * ub + col;
    f16x8 bf[4][4];    // [gate][kf]; L0 kf=2,3 all-zero (unused on L0 path)
#pragma unroll
    for (int g = 0; g < 4; ++g) {
#pragma unroll
        for (int kf = 0; kf < 4; ++kf) {
            f16x8 v;
#pragma unroll
            for (int e = 0; e < 8; ++e)
                v[e] = (f16)welem(layer, g, u, kf * 32 + 8 * kg + e,
                                  W_ih0, W_hh0, b0, W_ih1, W_hh1, b1);
            bf[g][kf] = v;
        }
    }

    __syncthreads();   // LAST barrier in the kernel

    volatile u32* vf0 = &f0[0][0];
    volatile u32* vf1 = &f1[0][0];
    float cst[4] = {0.f, 0.f, 0.f, 0.f};   // cell state (L2E2 domain)
    const f32x4 z = {0.f, 0.f, 0.f, 0.f};

    if (layer == 0) {
        // =================== L0 gang: free-running producer ===================
        for (int s = 0; s < TT; ++s) {
            wait_gang(vf0, (u32)s);                 // gang finished step s-1
            const int rs = (s + 3) & 3, ws = s & 3;
            const f16x8 a0 = *reinterpret_cast<const f16x8*>(&ring[rs][col][8 * kg]);
            const f16x8 a1 = *reinterpret_cast<const f16x8*>(&ring[rs][col][32 + 8 * kg]);
            f32x4 acc[4];
            __builtin_amdgcn_s_setprio(1);
#pragma unroll
            for (int g = 0; g < 4; ++g) {
                f32x4 c = __builtin_amdgcn_mfma_f32_16x16x32_f16(a0, bf[g][0], z, 0, 0, 0);
                acc[g]  = __builtin_amdgcn_mfma_f32_16x16x32_f16(a1, bf[g][1], c, 0, 0, 0);
            }
            __builtin_amdgcn_s_setprio(0);
            u16 hw[4];
#pragma unroll
            for (int r = 0; r < 4; ++r) {
                float hv;
                EWFUSED(acc[0][r], acc[1][r], acc[2][r], acc[3][r], cst[r], hv);
                hw[r] = __builtin_bit_cast(u16, (f16)hv);
            }
            // ring slot s%4 must be free of L1's step s-4 reads
            if (s >= 4) wait_gang(vf1, (u32)(s - 3));
            if (u < 50) {
#pragma unroll
                for (int r = 0; r < 4; ++r) ring[ws][4 * kg + r][u] = hw[r];
            }
            if (wid == 0 && lane < MB && (s + 1) < TT)
                *reinterpret_cast<u32*>(&ring[ws][lane][50]) = xpack[lane][s + 1];
            __threadfence_block();
            if (lane == 0) *(volatile u32*)&f0[gw][0] = (u32)(s + 1);
        }
    } else {
        // =================== L1 gang: free-running consumer ===================
        for (int t = 0; t < TT; ++t) {
            wait_gang2(vf0, (u32)(t + 1), vf1, (u32)t);  // h0(t) ready; own gang t-1
            const int rs = t & 3, wb = t & 1, rb = wb ^ 1;
            const f16x8 a0 = *reinterpret_cast<const f16x8*>(&ring[rs][col][8 * kg]);
            const f16x8 a1 = *reinterpret_cast<const f16x8*>(&ring[rs][col][32 + 8 * kg]);
            const f16x8 a2 = *reinterpret_cast<const f16x8*>(&h1b[rb][col][8 * kg]);
            const f16x8 a3 = *reinterpret_cast<const f16x8*>(&h1b[rb][col][32 + 8 * kg]);
            f32x4 acc[4];
            __builtin_amdgcn_s_setprio(1);
#pragma unroll
            for (int g = 0; g < 4; ++g) {
                // two independent 2-chains + add: halves serial MFMA latency
                f32x4 cA = __builtin_amdgcn_mfma_f32_16x16x32_f16(a0, bf[g][0], z, 0, 0, 0);
                f32x4 cB = __builtin_amdgcn_mfma_f32_16x16x32_f16(a2, bf[g][2], z, 0, 0, 0);
                cA = __builtin_amdgcn_mfma_f32_16x16x32_f16(a1, bf[g][1], cA, 0, 0, 0);
                cB = __builtin_amdgcn_mfma_f32_16x16x32_f16(a3, bf[g][3], cB, 0, 0, 0);
                acc[g] = cA + cB;
            }
            __builtin_amdgcn_s_setprio(0);
            u16 hw[4]; float hf[4];
#pragma unroll
            for (int r = 0; r < 4; ++r) {
                float hv;
                EWFUSED(acc[0][r], acc[1][r], acc[2][r], acc[3][r], cst[r], hv);
                hw[r] = __builtin_bit_cast(u16, (f16)hv);
                hf[r] = hv;
            }
            if (u < 50) {
#pragma unroll
                for (int r = 0; r < 4; ++r) h1b[wb][4 * kg + r][u] = hw[r];
                if (t == TT - 1) {
#pragma unroll
                    for (int r = 0; r < 4; ++r) hfin[4 * kg + r][u] = hf[r];
                }
            }
            __threadfence_block();
            if (lane == 0) *(volatile u32*)&f1[gw][0] = (u32)(t + 1);
        }
        // ---- final linear head on fp32 h1[T-1] (after whole L1 gang done) ----
        if (wid == 4) {
            wait_gang(vf1, (u32)TT);
            if (lane < MB) {
                float d = b_fc[0];
#pragma unroll
                for (int uu = 0; uu < 50; ++uu)
                    d = fmaf(W_fc[uu], hfin[lane][uu], d);
                out[bbase + lane] = d;
            }
        }
    }
}

extern "C" void kernel_launch(void* const* d_in, const int* in_sizes, int n_in,
                              void* d_out, int out_size, void* d_ws, size_t ws_size,
                              hipStream_t stream) {
    const float* x     = (const float*)d_in[0];
    const float* W_ih0 = (const float*)d_in[1];
    const float* W_hh0 = (const float*)d_in[2];
    const float* b0    = (const float*)d_in[3];
    const float* W_ih1 = (const float*)d_in[4];
    const float* W_hh1 = (const float*)d_in[5];
    const float* b1    = (const float*)d_in[6];
    const float* W_fc  = (const float*)d_in[7];
    const float* b_fc  = (const float*)d_in[8];
    float* out = (float*)d_out;

    const int B = in_sizes[0] / (TT * 2);    // 4096
    dim3 grid(B / MB), block(BLK);           // 256 blocks = 1 per CU
    hipLaunchKernelGGL(lstm2_flags, grid, block, 0, stream,
                       x, W_ih0, W_hh0, b0, W_ih1, W_hh1, b1, W_fc, b_fc, out);
}

// Round 13
// 426.316 us; speedup vs baseline: 1.0425x; 1.0242x over previous
//
#include <hip/hip_runtime.h>

// 2-layer LSTM (H=50) + linear head — MFMA v8: barrier loop + chain shaving.
//
// Rounds 6-12 ledger: barrier=399us, async-atomic=399, flags=437, 3w/SIMD=444
// -> period (~1870 cyc/step) is chain+lockstep-bound, not protocol-bound.
// This round: keep round-6's 8-wave barrier loop (lowest jitter), cut the
// per-step chain and issue:
//  - fused-rcp EW: 8 trans/body (5 exp2 + 3 rcp) instead of 10
//  - x-projection + bias moved from the K-dim into the MFMA C-INPUT:
//      L0: acc = mfma(a1,bf1, mfma(a0,bf0, xacc[g])), xacc computed on VALU
//      from static xpack for step t+1 AFTER the h-writes (hidden in
//      pre-barrier slack). Deletes the per-step x-copy LDS writes entirely.
//      L1: bias as a precomputed f32x4 splat C-input.
//  - L1 MFMA: two independent 2-chains + add (halves serial latency)
//  - s_setprio(1) around MFMA clusters
//
// Structure: block = 512 thr (8 waves), MB=16 batches, grid 256 = 1/CU.
//   waves 0-3: L0 (ub=wid), waves 4-7: L1 (ub=wid-4), L1 lags one step.
// hc[2] double buffer, rows (f16): [h0 0..49 | 0 pad | h1 @64..113 | 0 pad].
// Weights pre-scaled (i,f,o: -log2e; g: +2log2e; c kept in 2log2e domain).
// One __syncthreads per step.

typedef _Float16 f16;
typedef f16  f16x8 __attribute__((ext_vector_type(8)));
typedef float f32x4 __attribute__((ext_vector_type(4)));
typedef unsigned short u16;
typedef unsigned int   u32;

#define TT   512
#define MB   16     // batches per block (= MFMA M)
#define KP   136    // hc row length in f16 (128 + 8 pad)
#define XTP  513    // xpack row pad (and +1 slot so [TT] index is in-bounds)
#define BLK  512    // 8 waves

#define EXP2(v) __builtin_amdgcn_exp2f(v)
__device__ __forceinline__ float rcp_(float v) { return __builtin_amdgcn_rcpf(v); }

#define L2E  1.4426950408889634f
#define L2E2 2.8853900817779268f

// Weight element for B-fragment position (layer, gate g, out-unit u, k),
// pre-scaled: gates i,f,o (g=0,1,3) by -log2e; gate g (g=2) by +2*log2e.
// x/bias no longer live in K (handled via MFMA C-input).
__device__ __forceinline__ float welem(int layer, int g, int u, int k,
        const float* __restrict__ Whh0,
        const float* __restrict__ Wih1, const float* __restrict__ Whh1) {
    if (u >= 50) return 0.0f;
    const float s = (g == 2) ? L2E2 : -L2E;
    const int row = g * 50 + u;           // PyTorch gate order i,f,g,o
    if (layer == 0) {
        return (k < 50) ? s * Whh0[row * 50 + k] : 0.0f;
    } else {
        if (k < 50)             return s * Wih1[row * 50 + k];
        if (k >= 64 && k < 114) return s * Whh1[row * 50 + (k - 64)];
        return 0.0f;
    }
}

// Fused elementwise: pre-scaled gate sums, cell state in L2E2 domain.
// i*g' = L2E2*(eG-1)*rcp((1+eI)(1+eG)); h = (eC-1)*rcp((1+eO)(eC+1)).
#define EWFUSED(YI, YF, YG, YO, CS, HOUT)                                     \
    {                                                                         \
        const float eI = EXP2(YI);                                            \
        const float eF = EXP2(YF);                                            \
        const float eG = EXP2(YG);                                            \
        const float eO = EXP2(YO);                                            \
        const float fg  = rcp_(1.0f + eF);                                    \
        const float num = fmaf(L2E2, eG, -L2E2);                              \
        const float igg = num * rcp_((1.0f + eI) * (1.0f + eG));              \
        CS = fmaf(fg, CS, igg);                                               \
        const float cc = fminf(fmaxf(CS, -80.0f), 80.0f);                     \
        const float eC = EXP2(cc);                                            \
        HOUT = (eC - 1.0f) * rcp_((1.0f + eO) * (eC + 1.0f));                 \
    }

extern "C" __global__ void __launch_bounds__(BLK, 2)
lstm2_v8(const float* __restrict__ x,
         const float* __restrict__ W_ih0, const float* __restrict__ W_hh0,
         const float* __restrict__ b0,
         const float* __restrict__ W_ih1, const float* __restrict__ W_hh1,
         const float* __restrict__ b1,
         const float* __restrict__ W_fc,  const float* __restrict__ b_fc,
         float* __restrict__ out)
{
    __shared__ __align__(16) u16 hc[2][MB][KP];   // 8.7 KB double-buffered state
    __shared__ u32   xpack[MB][XTP];              // 32.8 KB packed f16 x pairs
    __shared__ float hfin[MB][52];                // final h1 fp32 for the head

    const int tid   = threadIdx.x;
    const int lane  = tid & 63;
    const int wid   = tid >> 6;        // 0..7
    const int layer = wid >> 2;        // waves 0-3: L0, waves 4-7: L1
    const int ub    = wid & 3;         // unit-block (16 units)
    const int col   = lane & 15;       // A-row (batch) / B-col (unit) / D-col
    const int kg    = lane >> 4;       // k-octet / D-row group
    const int bbase = blockIdx.x * MB;

    // ---- stage x -> packed f16 pairs (coalesced float2 loads) ----
    for (int idx = tid; idx < MB * TT; idx += BLK) {
        const int b = idx >> 9, t = idx & (TT - 1);
        const float2 v = *reinterpret_cast<const float2*>(
            x + ((size_t)(bbase + b) * TT + t) * 2);
        xpack[b][t] = (u32)__builtin_bit_cast(u16, (f16)v.x)
                    | ((u32)__builtin_bit_cast(u16, (f16)v.y) << 16);
    }
    // ---- zero hc (both buffers; pads stay 0 forever; h(-1)=0) ----
    {
        u32* hcU = reinterpret_cast<u32*>(&hc[0][0][0]);
        for (int i = tid; i < 2 * MB * KP / 2; i += BLK) hcU[i] = 0;
    }

    // ---- static weight B-fragments (constant-bound loops -> registers) ----
    // B map: lane l, elem e <-> B[k = kf*32 + 8*kg + e][n = col]; identical
    // (lane,e)->k map as the A reads -> in-octet permutations cancel.
    const int u = 16 * ub + col;
    f16x8 bf[4][4];    // [gate][kf]; L0 kf=2,3 all-zero (unused on L0 path)
#pragma unroll
    for (int g = 0; g < 4; ++g) {
#pragma unroll
        for (int kf = 0; kf < 4; ++kf) {
            f16x8 v;
#pragma unroll
            for (int e = 0; e < 8; ++e)
                v[e] = (f16)welem(layer, g, u, kf * 32 + 8 * kg + e,
                                  W_hh0, W_ih1, W_hh1);
            bf[g][kf] = v;
        }
    }
    // ---- per-gate x-weights / bias (pre-scaled), and L1 bias C-input ----
    float wxa[4], wxb[4], bsc[4];
    f32x4 biasC[4];
#pragma unroll
    for (int g = 0; g < 4; ++g) {
        const float s = (g == 2) ? L2E2 : -L2E;
        const int row = g * 50 + ((u < 50) ? u : 0);
        const float z50 = (u < 50) ? 1.0f : 0.0f;   // pad units contribute 0
        if (layer == 0) {
            wxa[g] = s * W_ih0[row * 2 + 0] * z50;
            wxb[g] = s * W_ih0[row * 2 + 1] * z50;
            bsc[g] = s * b0[row] * z50;
        } else {
            const float bb = s * b1[row] * z50;
            biasC[g] = (f32x4){bb, bb, bb, bb};
            wxa[g] = wxb[g] = bsc[g] = 0.0f;
        }
    }

    float cst[4] = {0.f, 0.f, 0.f, 0.f};   // cell state (L2E2 domain)
    const f32x4 z = {0.f, 0.f, 0.f, 0.f};
    const int hbase = layer ? 64 : 0;

    __syncthreads();

    // L0's x-projection C-input for step 0 (from static xpack; VALU only)
    f32x4 xc[4];
    if (layer == 0) {
#pragma unroll
        for (int r = 0; r < 4; ++r) {
            const u32 xp = xpack[4 * kg + r][0];
            const float x0 = (float)__builtin_bit_cast(f16, (u16)(xp & 0xffff));
            const float x1 = (float)__builtin_bit_cast(f16, (u16)(xp >> 16));
#pragma unroll
            for (int g = 0; g < 4; ++g)
                xc[g][r] = fmaf(wxa[g], x0, fmaf(wxb[g], x1, bsc[g]));
        }
    }

    for (int it = 0; it <= TT; ++it) {
        const int p = it & 1, q = p ^ 1;
        f32x4 acc[4];

        if (layer == 0) {
            if (it < TT) {
                // A: h0(it-1) from hc[p]
                const f16x8 a0 = *reinterpret_cast<const f16x8*>(&hc[p][col][8 * kg]);
                const f16x8 a1 = *reinterpret_cast<const f16x8*>(&hc[p][col][32 + 8 * kg]);
                __builtin_amdgcn_s_setprio(1);
#pragma unroll
                for (int g = 0; g < 4; ++g) {
                    f32x4 c = __builtin_amdgcn_mfma_f32_16x16x32_f16(a0, bf[g][0], xc[g], 0, 0, 0);
                    acc[g]  = __builtin_amdgcn_mfma_f32_16x16x32_f16(a1, bf[g][1], c, 0, 0, 0);
                }
                __builtin_amdgcn_s_setprio(0);
#pragma unroll
                for (int r = 0; r < 4; ++r) {
                    float hv;
                    EWFUSED(acc[0][r], acc[1][r], acc[2][r], acc[3][r], cst[r], hv);
                    if (u < 50)
                        hc[q][4 * kg + r][u] = __builtin_bit_cast(u16, (f16)hv);
                }
                // precompute next step's x C-input (hides in pre-barrier slack;
                // xpack[.][TT] read is in-bounds via XTP pad, value unused)
#pragma unroll
                for (int r = 0; r < 4; ++r) {
                    const u32 xp = xpack[4 * kg + r][it + 1];
                    const float x0 = (float)__builtin_bit_cast(f16, (u16)(xp & 0xffff));
                    const float x1 = (float)__builtin_bit_cast(f16, (u16)(xp >> 16));
#pragma unroll
                    for (int g = 0; g < 4; ++g)
                        xc[g][r] = fmaf(wxa[g], x0, fmaf(wxb[g], x1, bsc[g]));
                }
            }
        } else {
            if (it >= 1) {
                // A: h0(it-1) and h1(it-2) from hc[p]
                const f16x8 a0 = *reinterpret_cast<const f16x8*>(&hc[p][col][8 * kg]);
                const f16x8 a1 = *reinterpret_cast<const f16x8*>(&hc[p][col][32 + 8 * kg]);
                const f16x8 a2 = *reinterpret_cast<const f16x8*>(&hc[p][col][64 + 8 * kg]);
                const f16x8 a3 = *reinterpret_cast<const f16x8*>(&hc[p][col][96 + 8 * kg]);
                __builtin_amdgcn_s_setprio(1);
#pragma unroll
                for (int g = 0; g < 4; ++g) {
                    // two independent 2-chains + add: halves serial MFMA latency
                    f32x4 cA = __builtin_amdgcn_mfma_f32_16x16x32_f16(a0, bf[g][0], biasC[g], 0, 0, 0);
                    f32x4 cB = __builtin_amdgcn_mfma_f32_16x16x32_f16(a2, bf[g][2], z, 0, 0, 0);
                    cA = __builtin_amdgcn_mfma_f32_16x16x32_f16(a1, bf[g][1], cA, 0, 0, 0);
                    cB = __builtin_amdgcn_mfma_f32_16x16x32_f16(a3, bf[g][3], cB, 0, 0, 0);
                    acc[g] = cA + cB;
                }
                __builtin_amdgcn_s_setprio(0);
#pragma unroll
                for (int r = 0; r < 4; ++r) {
                    float hv;
                    EWFUSED(acc[0][r], acc[1][r], acc[2][r], acc[3][r], cst[r], hv);
                    if (u < 50) {
                        hc[q][4 * kg + r][64 + u] = __builtin_bit_cast(u16, (f16)hv);
                        if (it == TT) hfin[4 * kg + r][u] = hv;
                    }
                }
            }
        }
        __syncthreads();
    }

    // ===== final linear head on fp32 h1[T-1] =====
    if (tid < MB) {
        float d = b_fc[0];
#pragma unroll
        for (int uu = 0; uu < 50; ++uu) d = fmaf(W_fc[uu], hfin[tid][uu], d);
        out[bbase + tid] = d;
    }
}

extern "C" void kernel_launch(void* const* d_in, const int* in_sizes, int n_in,
                              void* d_out, int out_size, void* d_ws, size_t ws_size,
                              hipStream_t stream) {
    const float* x     = (const float*)d_in[0];
    const float* W_ih0 = (const float*)d_in[1];
    const float* W_hh0 = (const float*)d_in[2];
    const float* b0    = (const float*)d_in[3];
    const float* W_ih1 = (const float*)d_in[4];
    const float* W_hh1 = (const float*)d_in[5];
    const float* b1    = (const float*)d_in[6];
    const float* W_fc  = (const float*)d_in[7];
    const float* b_fc  = (const float*)d_in[8];
    float* out = (float*)d_out;

    const int B = in_sizes[0] / (TT * 2);    // 4096
    dim3 grid(B / MB), block(BLK);           // 256 blocks = 1 per CU
    hipLaunchKernelGGL(lstm2_v8, grid, block, 0, stream,
                       x, W_ih0, W_hh0, b0, W_ih1, W_hh1, b1, W_fc, b_fc, out);
}

// Round 14
// 373.555 us; speedup vs baseline: 1.1898x; 1.1412x over previous
//
#include <hip/hip_runtime.h>

// 2-layer LSTM (H=50) + linear head — MFMA v9: round-6 structure, minimal delta.
//
// Single composite change vs round 6 (399 us, the best measured):
//   fused-rcp elementwise + weight prescale (proven numerics, r9-r13,
//   absmax 4.88e-4 identical): 8 trans/body (5 exp2 + 3 rcp) instead of
//   r6's 10 trans + 5 hidden muls (__expf = mul+v_exp each).
// Everything else is round-6 verbatim: 8 waves (waves 0-3 L0, 4-7 L1, L1
// lags one step), MB=16, grid=256 (1 block/CU), hc[2] double buffer with
// x at k=50,51 and bias-slot 1.0 at k=52 (bias folded into K, PRESCALED in
// welem), per-step x copy by wave 0, one __syncthreads per step, static
// B-fragments in registers, L1 serial 4-chain MFMA, s_setprio around MFMA.
//
// Decision rule (pre-committed): if dur >= ~392 us, the ~1865 cyc/step
// period is this decomposition's sync+convoy floor -> declare roofline.

typedef _Float16 f16;
typedef f16  f16x8 __attribute__((ext_vector_type(8)));
typedef float f32x4 __attribute__((ext_vector_type(4)));
typedef unsigned short u16;
typedef unsigned int   u32;

#define TT   512
#define MB   16     // batches per block (= MFMA M)
#define KP   136    // hc row length in f16 (128 + 8 pad)
#define XTP  513    // xpack row pad
#define BLK  512    // 8 waves

#define EXP2(v) __builtin_amdgcn_exp2f(v)
__device__ __forceinline__ float rcp_(float v) { return __builtin_amdgcn_rcpf(v); }

#define L2E  1.4426950408889634f
#define L2E2 2.8853900817779268f

// Weight element for B-fragment position (layer, gate g, out-unit u, k),
// pre-scaled: gates i,f,o (g=0,1,3) by -log2e; gate g (g=2) by +2*log2e.
// K layout: L0 [Whh0 0..49 | Wih0 50,51 | b0 @52]; L1 [Wih1 0..49 | b1 @52 |
// Whh1 @64..113]; all other k = 0.
__device__ __forceinline__ float welem(int layer, int g, int u, int k,
        const float* __restrict__ Wih0, const float* __restrict__ Whh0,
        const float* __restrict__ b0,
        const float* __restrict__ Wih1, const float* __restrict__ Whh1,
        const float* __restrict__ b1) {
    if (u >= 50) return 0.0f;
    const float s = (g == 2) ? L2E2 : -L2E;
    const int row = g * 50 + u;           // PyTorch gate order i,f,g,o
    if (layer == 0) {
        if (k < 50)  return s * Whh0[row * 50 + k];
        if (k < 52)  return s * Wih0[row * 2 + (k - 50)];
        if (k == 52) return s * b0[row];
        return 0.0f;
    } else {
        if (k < 50)             return s * Wih1[row * 50 + k];
        if (k == 52)            return s * b1[row];
        if (k >= 64 && k < 114) return s * Whh1[row * 50 + (k - 64)];
        return 0.0f;
    }
}

// Fused elementwise: pre-scaled gate sums, cell state kept in 2log2e domain.
// i*g' = L2E2*(eG-1)*rcp((1+eI)(1+eG)); h = (eC-1)*rcp((1+eO)(eC+1)).
#define EWFUSED(YI, YF, YG, YO, CS, HOUT)                                     \
    {                                                                         \
        const float eI = EXP2(YI);                                            \
        const float eF = EXP2(YF);                                            \
        const float eG = EXP2(YG);                                            \
        const float eO = EXP2(YO);                                            \
        const float fg  = rcp_(1.0f + eF);                                    \
        const float num = fmaf(L2E2, eG, -L2E2);                              \
        const float igg = num * rcp_((1.0f + eI) * (1.0f + eG));              \
        CS = fmaf(fg, CS, igg);                                               \
        const float cc = fminf(fmaxf(CS, -80.0f), 80.0f);                     \
        const float eC = EXP2(cc);                                            \
        HOUT = (eC - 1.0f) * rcp_((1.0f + eO) * (eC + 1.0f));                 \
    }

extern "C" __global__ void __launch_bounds__(BLK, 2)
lstm2_v9(const float* __restrict__ x,
         const float* __restrict__ W_ih0, const float* __restrict__ W_hh0,
         const float* __restrict__ b0,
         const float* __restrict__ W_ih1, const float* __restrict__ W_hh1,
         const float* __restrict__ b1,
         const float* __restrict__ W_fc,  const float* __restrict__ b_fc,
         float* __restrict__ out)
{
    __shared__ __align__(16) u16 hc[2][MB][KP];   // 8.7 KB double-buffered state
    __shared__ u32   xpack[MB][XTP];              // 32.8 KB packed f16 x pairs
    __shared__ float hfin[MB][52];                // final h1 (fp32) for the head

    const int tid   = threadIdx.x;
    const int lane  = tid & 63;
    const int wid   = tid >> 6;        // 0..7
    const int layer = wid >> 2;        // waves 0-3: L0, waves 4-7: L1
    const int ub    = wid & 3;         // unit-block (16 units)
    const int col   = lane & 15;       // A-row (batch) / B-col (unit) / D-col
    const int kg    = lane >> 4;       // k-octet / D-row group
    const int bbase = blockIdx.x * MB;

    // ---- stage x -> packed f16 pairs in LDS (coalesced float2 loads) ----
    for (int idx = tid; idx < MB * TT; idx += BLK) {
        const int b = idx >> 9, t = idx & (TT - 1);
        const float2 v = *reinterpret_cast<const float2*>(
            x + ((size_t)(bbase + b) * TT + t) * 2);
        xpack[b][t] = (u32)__builtin_bit_cast(u16, (f16)v.x)
                    | ((u32)__builtin_bit_cast(u16, (f16)v.y) << 16);
    }
    // ---- zero hc (both buffers; pads stay 0 forever) ----
    {
        u32* hcU = reinterpret_cast<u32*>(&hc[0][0][0]);
        for (int i = tid; i < 2 * MB * KP / 2; i += BLK) hcU[i] = 0;
    }
    __syncthreads();
    // bias slot (k=52) = f16 1.0 in both buffers; x(0) into buffer 0
    if (tid < 32) hc[tid >> 4][tid & 15][52] = (u16)0x3C00;
    else if (tid < 48)
        *reinterpret_cast<u32*>(&hc[0][tid - 32][50]) = xpack[tid - 32][0];

    // ---- static weight B-fragments (constant-bound loops -> registers) ----
    // B map: lane l, elem e <-> B[k = kf*32 + 8*kg + e][n = col]; identical
    // (lane,e)->k map as the A reads -> in-octet permutations cancel.
    const int u = 16 * ub + col;
    f16x8 bf[4][4];    // [gate][kf]; L0 kf=2,3 all-zero (unused on L0 path)
#pragma unroll
    for (int g = 0; g < 4; ++g) {
#pragma unroll
        for (int kf = 0; kf < 4; ++kf) {
            f16x8 v;
#pragma unroll
            for (int e = 0; e < 8; ++e)
                v[e] = (f16)welem(layer, g, u, kf * 32 + 8 * kg + e,
                                  W_ih0, W_hh0, b0, W_ih1, W_hh1, b1);
            bf[g][kf] = v;
        }
    }

    float cst[4] = {0.f, 0.f, 0.f, 0.f};   // cell state (L2E2 domain)
    const f32x4 z = {0.f, 0.f, 0.f, 0.f};
    __syncthreads();

    for (int it = 0; it <= TT; ++it) {
        const int p = it & 1, q = p ^ 1;
        f32x4 acc[4];

        if (layer == 0) {
            if (it < TT) {
                // A: lane l, elem e <-> hc[p][batch = col][k = kf*32 + 8*kg + e]
                const f16x8 a0 = *reinterpret_cast<const f16x8*>(&hc[p][col][8 * kg]);
                const f16x8 a1 = *reinterpret_cast<const f16x8*>(&hc[p][col][32 + 8 * kg]);
                __builtin_amdgcn_s_setprio(1);
#pragma unroll
                for (int g = 0; g < 4; ++g) {
                    f32x4 c = __builtin_amdgcn_mfma_f32_16x16x32_f16(a0, bf[g][0], z, 0, 0, 0);
                    acc[g]  = __builtin_amdgcn_mfma_f32_16x16x32_f16(a1, bf[g][1], c, 0, 0, 0);
                }
                __builtin_amdgcn_s_setprio(0);
                // D map (HW-verified): D[row = 4*kg + r][col]; row=batch, col=unit
                if (u < 50) {
#pragma unroll
                    for (int r = 0; r < 4; ++r) {
                        float hv;
                        EWFUSED(acc[0][r], acc[1][r], acc[2][r], acc[3][r], cst[r], hv);
                        hc[q][4 * kg + r][u] = __builtin_bit_cast(u16, (f16)hv);
                    }
                }
            }
        } else {
            if (it >= 1) {
                const f16x8 a0 = *reinterpret_cast<const f16x8*>(&hc[p][col][8 * kg]);
                const f16x8 a1 = *reinterpret_cast<const f16x8*>(&hc[p][col][32 + 8 * kg]);
                const f16x8 a2 = *reinterpret_cast<const f16x8*>(&hc[p][col][64 + 8 * kg]);
                const f16x8 a3 = *reinterpret_cast<const f16x8*>(&hc[p][col][96 + 8 * kg]);
                __builtin_amdgcn_s_setprio(1);
#pragma unroll
                for (int g = 0; g < 4; ++g) {
                    f32x4 c = __builtin_amdgcn_mfma_f32_16x16x32_f16(a0, bf[g][0], z, 0, 0, 0);
                    c       = __builtin_amdgcn_mfma_f32_16x16x32_f16(a1, bf[g][1], c, 0, 0, 0);
                    c       = __builtin_amdgcn_mfma_f32_16x16x32_f16(a2, bf[g][2], c, 0, 0, 0);
                    acc[g]  = __builtin_amdgcn_mfma_f32_16x16x32_f16(a3, bf[g][3], c, 0, 0, 0);
                }
                __builtin_amdgcn_s_setprio(0);
                if (u < 50) {
#pragma unroll
                    for (int r = 0; r < 4; ++r) {
                        float hv;
                        EWFUSED(acc[0][r], acc[1][r], acc[2][r], acc[3][r], cst[r], hv);
                        hc[q][4 * kg + r][64 + u] = __builtin_bit_cast(u16, (f16)hv);
                        if (it == TT) hfin[4 * kg + r][u] = hv;
                    }
                }
            }
        }
        // next step's x into hc[q] slots 50,51 (one u32 per batch, wave 0)
        if (wid == 0 && lane < MB && (it + 1) < TT)
            *reinterpret_cast<u32*>(&hc[q][lane][50]) = xpack[lane][it + 1];

        __syncthreads();
    }

    // ===== final linear head on fp32 h1[T-1] =====
    if (tid < MB) {
        float d = b_fc[0];
#pragma unroll
        for (int uu = 0; uu < 50; ++uu) d = fmaf(W_fc[uu], hfin[tid][uu], d);
        out[bbase + tid] = d;
    }
}

extern "C" void kernel_launch(void* const* d_in, const int* in_sizes, int n_in,
                              void* d_out, int out_size, void* d_ws, size_t ws_size,
                              hipStream_t stream) {
    const float* x     = (const float*)d_in[0];
    const float* W_ih0 = (const float*)d_in[1];
    const float* W_hh0 = (const float*)d_in[2];
    const float* b0    = (const float*)d_in[3];
    const float* W_ih1 = (const float*)d_in[4];
    const float* W_hh1 = (const float*)d_in[5];
    const float* b1    = (const float*)d_in[6];
    const float* W_fc  = (const float*)d_in[7];
    const float* b_fc  = (const float*)d_in[8];
    float* out = (float*)d_out;

    const int B = in_sizes[0] / (TT * 2);    // 4096
    dim3 grid(B / MB), block(BLK);           // 256 blocks = 1 per CU
    hipLaunchKernelGGL(lstm2_v9, grid, block, 0, stream,
                       x, W_ih0, W_hh0, b0, W_ih1, W_hh1, b1, W_fc, b_fc, out);
}